// Round 4
// baseline (661.045 us; speedup 1.0000x reference)
//
#include <hip/hip_runtime.h>
#include <hip/hip_bf16.h>
#include <cstdint>

#define BATCH 4096
#define LAT   2048
#define NFREQ 2074
#define KPAD  2112   // NFREQ padded up to a multiple of 64 (zero-filled); 66 K-iters

typedef __bf16 bf16x8 __attribute__((ext_vector_type(8)));
typedef float  f32x4  __attribute__((ext_vector_type(4)));

__device__ __forceinline__ unsigned short f2bf(float f) {
    unsigned int u = __float_as_uint(f);
    u = (u + 0x7fffu + ((u >> 16) & 1u)) >> 16;
    return (unsigned short)u;
}

__device__ __forceinline__ void gload_lds16(const unsigned short* g, unsigned short* l) {
    __builtin_amdgcn_global_load_lds(
        (const __attribute__((address_space(1))) unsigned int*)g,
        (__attribute__((address_space(3))) unsigned int*)l,
        16, 0, 0);
}

// ---------------------------------------------------------------------------
// prep: blocks [0,4096)    -> cast x fp32 -> bf16 (8 elem/thread) + init max
//       blocks [4096,5152) -> transpose+cast W  -> WT  [LAT][KPAD]
//       blocks [5152,6208) -> transpose+cast cb -> cosT[LAT][KPAD]
__global__ void prep_kernel(const float* __restrict__ x,
                            const float* __restrict__ W,
                            const float* __restrict__ cb,
                            unsigned short* __restrict__ xb,
                            unsigned short* __restrict__ WT,
                            unsigned short* __restrict__ cosT,
                            float* __restrict__ maxp) {
    __shared__ float t[64][65];
    const int bid = blockIdx.x;
    const int tid = threadIdx.x;
    if (bid < 4096) {
        int i = bid * 256 + tid;
        const float4* x4 = (const float4*)x;
        float4 a = x4[2 * i];
        float4 b = x4[2 * i + 1];
        union { unsigned short us[8]; uint4 v; } p;
        p.us[0] = f2bf(a.x); p.us[1] = f2bf(a.y); p.us[2] = f2bf(a.z); p.us[3] = f2bf(a.w);
        p.us[4] = f2bf(b.x); p.us[5] = f2bf(b.y); p.us[6] = f2bf(b.z); p.us[7] = f2bf(b.w);
        ((uint4*)xb)[i] = p.v;
        if (i == 0) *maxp = -__builtin_inff();
        return;
    }
    int b2 = bid - 4096;
    const float* in     = (b2 < 1056) ? W  : cb;
    unsigned short* out = (b2 < 1056) ? WT : cosT;
    if (b2 >= 1056) b2 -= 1056;
    const int c0 = (b2 % 32) * 64;
    const int r0 = (b2 / 32) * 64;
    for (int i = tid; i < 4096; i += 256) {
        int rr = i >> 6, cc = i & 63;
        int r = r0 + rr;
        float v = (r < NFREQ) ? in[(size_t)r * LAT + c0 + cc] : 0.0f;
        t[rr][cc] = v;
    }
    __syncthreads();
    for (int i = tid; i < 4096; i += 256) {
        int cc = i >> 6, rr = i & 63;
        out[(size_t)(c0 + cc) * KPAD + (r0 + rr)] = f2bf(t[rr][cc]);
    }
}

// ---------------------------------------------------------------------------
// Split-K GEMM: C[m][n] += sum_{k in split z} A[m][k] * Bt[n][k]  (fp32 atomic)
// Round-2's proven loop: 128x128 block, 4 waves in 2x2, BK=32, 3-stage
// circular LDS, one raw s_barrier per iter with vmcnt(4) straddle (the 4
// prefetch DMAs for tile j+1 stay in flight across the barrier). Fetch
// mapping is the COALESCED one (lane groups of 4 read 64 contiguous bytes):
// round 3 proved the scattered mapping costs ~1.6x latency while the bank
// conflicts it removed were only 0.01% of cycles.
// blockIdx.z = K-split index; accumulate via native global_atomic_add_f32
// into a zeroed fp32 C (harness-legal: hipMemsetAsync on stream).
template <int N, int K, int NIT>
__global__ __launch_bounds__(256)
void gemm_splitk_kernel(const unsigned short* __restrict__ A,
                        const unsigned short* __restrict__ Bt,
                        float* __restrict__ C) {
    __shared__ alignas(16) unsigned short As[3][128 * 32];
    __shared__ alignas(16) unsigned short Bs[3][128 * 32];

    const int tid  = threadIdx.x;
    const int wave = tid >> 6;
    const int lane = tid & 63;
    const int wm   = (wave >> 1) * 64;
    const int wn   = (wave & 1) * 64;
    const int quad = lane >> 4;
    const int l16  = lane & 15;

    const int mBase = blockIdx.y * 128;
    const int nBase = blockIdx.x * 128;
    const int kOff  = blockIdx.z * (NIT * 32);

    // staging: each wave fills two 16-row (1 KiB) chunks of As and Bs;
    // coalesced: 4 consecutive lanes cover 64 contiguous bytes of one row.
    const int srow = lane >> 2;        // 0..15 row within chunk
    const int sk   = (lane & 3) * 8;   // 0,8,16,24 k-offset

    const unsigned short* Ab1 = A  + (size_t)(mBase + wave * 16 + srow) * K + kOff + sk;
    const unsigned short* Ab2 = A  + (size_t)(mBase + (wave + 4) * 16 + srow) * K + kOff + sk;
    const unsigned short* Bb1 = Bt + (size_t)(nBase + wave * 16 + srow) * K + kOff + sk;
    const unsigned short* Bb2 = Bt + (size_t)(nBase + (wave + 4) * 16 + srow) * K + kOff + sk;

    const int aoff1 = (wave * 16) * 32;
    const int aoff2 = ((wave + 4) * 16) * 32;

    // prologue: tile 0 into buffer 0
    gload_lds16(Ab1, &As[0][aoff1]);
    gload_lds16(Ab2, &As[0][aoff2]);
    gload_lds16(Bb1, &Bs[0][aoff1]);
    gload_lds16(Bb2, &Bs[0][aoff2]);

    f32x4 acc[4][4] = {};

    int bc = 0;
    for (int j = 0; j < NIT; ++j) {
        const int bn = (bc == 2) ? 0 : bc + 1;
        if (j + 1 < NIT) {
            const int k0 = (j + 1) * 32;
            gload_lds16(Ab1 + k0, &As[bn][aoff1]);
            gload_lds16(Ab2 + k0, &As[bn][aoff2]);
            gload_lds16(Bb1 + k0, &Bs[bn][aoff1]);
            gload_lds16(Bb2 + k0, &Bs[bn][aoff2]);
            asm volatile("s_waitcnt vmcnt(4)\n\ts_barrier" ::: "memory");
        } else {
            asm volatile("s_waitcnt vmcnt(0)\n\ts_barrier" ::: "memory");
        }

        bf16x8 af[4], bfr[4];
#pragma unroll
        for (int mi = 0; mi < 4; ++mi)
            af[mi] = *(const bf16x8*)&As[bc][(wm + mi * 16 + l16) * 32 + quad * 8];
#pragma unroll
        for (int ni = 0; ni < 4; ++ni)
            bfr[ni] = *(const bf16x8*)&Bs[bc][(wn + ni * 16 + l16) * 32 + quad * 8];
#pragma unroll
        for (int mi = 0; mi < 4; ++mi)
#pragma unroll
            for (int ni = 0; ni < 4; ++ni)
                acc[mi][ni] = __builtin_amdgcn_mfma_f32_16x16x32_bf16(
                    af[mi], bfr[ni], acc[mi][ni], 0, 0, 0);
        bc = bn;
    }

    // epilogue: C/D layout col = lane&15, row = quad*4 + reg; atomic fp32 add
#pragma unroll
    for (int mi = 0; mi < 4; ++mi)
#pragma unroll
        for (int ni = 0; ni < 4; ++ni) {
            int col = nBase + wn + ni * 16 + l16;
#pragma unroll
            for (int r = 0; r < 4; ++r) {
                int row = mBase + wm + mi * 16 + quad * 4 + r;
                unsafeAtomicAdd(&C[(size_t)row * N + col], acc[mi][ni][r]);
            }
        }
}

// ---------------------------------------------------------------------------
// cast C1f (fp32) -> C1 (bf16), 8 elements/thread
__global__ void cast_c1_kernel(const float* __restrict__ in,
                               unsigned short* __restrict__ out) {
    int i = blockIdx.x * blockDim.x + threadIdx.x;
    const float4* i4 = (const float4*)in;
    float4 a = i4[2 * i];
    float4 b = i4[2 * i + 1];
    union { unsigned short us[8]; uint4 v; } p;
    p.us[0] = f2bf(a.x); p.us[1] = f2bf(a.y); p.us[2] = f2bf(a.z); p.us[3] = f2bf(a.w);
    p.us[4] = f2bf(b.x); p.us[5] = f2bf(b.y); p.us[6] = f2bf(b.z); p.us[7] = f2bf(b.w);
    ((uint4*)out)[i] = p.v;
}

// ---------------------------------------------------------------------------
// global max over out (4 elements/thread, wave-reduce, one atomic per wave)
__global__ void max_kernel(const float* __restrict__ out, float* __restrict__ maxp) {
    int i = blockIdx.x * blockDim.x + threadIdx.x;
    float4 v = ((const float4*)out)[i];
    float m = fmaxf(fmaxf(v.x, v.y), fmaxf(v.z, v.w));
#pragma unroll
    for (int off = 32; off > 0; off >>= 1)
        m = fmaxf(m, __shfl_xor(m, off));
    if ((threadIdx.x & 63) == 0) {
        if (m >= 0.0f) atomicMax((int*)maxp, __float_as_int(m));
        else           atomicMin((unsigned int*)maxp, __float_as_uint(m));
    }
}

// ---------------------------------------------------------------------------
__global__ void scale_kernel(float* __restrict__ out, const float* __restrict__ maxp) {
    int i = blockIdx.x * blockDim.x + threadIdx.x;
    float inv = 1.0f / (*maxp);
    float4* o4 = (float4*)out;
    float4 v = o4[i];
    v.x *= inv; v.y *= inv; v.z *= inv; v.w *= inv;
    o4[i] = v;
}

// ---------------------------------------------------------------------------
extern "C" void kernel_launch(void* const* d_in, const int* in_sizes, int n_in,
                              void* d_out, int out_size, void* d_ws, size_t ws_size,
                              hipStream_t stream) {
    const float* x  = (const float*)d_in[0];  // (4096, 2048)
    const float* W  = (const float*)d_in[1];  // (2074, 2048)
    const float* cb = (const float*)d_in[2];  // (2074, 2048)

    char* ws = (char*)d_ws;
    unsigned short* xb   = (unsigned short*)ws;                                   // [4096][2048] bf16  16.8 MB
    unsigned short* WT   = (unsigned short*)(ws + (size_t)BATCH * LAT * 2);       // [2048][2112] bf16   8.7 MB
    unsigned short* cosT = (unsigned short*)((char*)WT + (size_t)LAT * KPAD * 2); //                     8.7 MB
    unsigned short* C1   = (unsigned short*)((char*)cosT + (size_t)LAT * KPAD * 2); // [2048][2048] bf16 8.4 MB
    float*          C1f  = (float*)((char*)C1 + (size_t)LAT * LAT * 2);           // [2048][2048] fp32  16.8 MB
    float*          maxp = (float*)((char*)C1f + (size_t)LAT * LAT * 4);
    float*          out  = (float*)d_out;

    // zero the atomic-accumulation targets (d_out/d_ws are re-poisoned to 0xAA
    // before every timed launch; hipMemsetAsync is graph-capturable)
    hipMemsetAsync(C1f, 0, (size_t)LAT * LAT * 4, stream);
    hipMemsetAsync(out, 0, (size_t)out_size * 4, stream);

    // 1. fused prep: cast x -> bf16 (+init max), transpose+cast W and cos_basis
    prep_kernel<<<4096 + 2 * 1056, 256, 0, stream>>>(x, W, cb, xb, WT, cosT, maxp);

    // 2. C1f[l2][l1] = sum_f cosT[l2,f] * WT[l1,f]   split-K=3, 768 blocks
    gemm_splitk_kernel<LAT, KPAD, 22>
        <<<dim3(LAT / 128, LAT / 128, 3), 256, 0, stream>>>(cosT, WT, C1f);

    // 3. cast C1f -> bf16 C1 (GEMM2's Bt operand)
    cast_c1_kernel<<<(LAT * LAT / 8) / 256, 256, 0, stream>>>(C1f, C1);

    // 4. out[b][l2] += sum_l1 xb[b][l1] * C1[l2][l1]   split-K=2, 1024 blocks
    gemm_splitk_kernel<LAT, LAT, 32>
        <<<dim3(LAT / 128, BATCH / 128, 2), 256, 0, stream>>>(xb, C1, out);

    // 5. global max of out
    max_kernel<<<(out_size / 4) / 256, 256, 0, stream>>>(out, maxp);

    // 6. out /= max
    scale_kernel<<<(out_size / 4) / 256, 256, 0, stream>>>(out, maxp);
}

// Round 5
// 203.245 us; speedup vs baseline: 3.2525x; 3.2525x over previous
//
#include <hip/hip_runtime.h>
#include <hip/hip_bf16.h>
#include <cstdint>

#define BATCH 4096
#define LAT   2048
#define NFREQ 2074
#define KPAD  2112   // NFREQ padded up to a multiple of 64 (zero-filled); 66 K-iters

typedef __bf16 bf16x8 __attribute__((ext_vector_type(8)));
typedef float  f32x4  __attribute__((ext_vector_type(4)));

__device__ __forceinline__ unsigned short f2bf(float f) {
    unsigned int u = __float_as_uint(f);
    u = (u + 0x7fffu + ((u >> 16) & 1u)) >> 16;
    return (unsigned short)u;
}

__device__ __forceinline__ void gload_lds16(const unsigned short* g, unsigned short* l) {
    __builtin_amdgcn_global_load_lds(
        (const __attribute__((address_space(1))) unsigned int*)g,
        (__attribute__((address_space(3))) unsigned int*)l,
        16, 0, 0);
}

// ---------------------------------------------------------------------------
// prep: blocks [0,4096)    -> cast x fp32 -> bf16 (8 elem/thread) + init max
//       blocks [4096,5152) -> transpose+cast W  -> WT  [LAT][KPAD]
//       blocks [5152,6208) -> transpose+cast cb -> cosT[LAT][KPAD]
__global__ void prep_kernel(const float* __restrict__ x,
                            const float* __restrict__ W,
                            const float* __restrict__ cb,
                            unsigned short* __restrict__ xb,
                            unsigned short* __restrict__ WT,
                            unsigned short* __restrict__ cosT,
                            float* __restrict__ maxp) {
    __shared__ float t[64][65];
    const int bid = blockIdx.x;
    const int tid = threadIdx.x;
    if (bid < 4096) {
        int i = bid * 256 + tid;
        const float4* x4 = (const float4*)x;
        float4 a = x4[2 * i];
        float4 b = x4[2 * i + 1];
        union { unsigned short us[8]; uint4 v; } p;
        p.us[0] = f2bf(a.x); p.us[1] = f2bf(a.y); p.us[2] = f2bf(a.z); p.us[3] = f2bf(a.w);
        p.us[4] = f2bf(b.x); p.us[5] = f2bf(b.y); p.us[6] = f2bf(b.z); p.us[7] = f2bf(b.w);
        ((uint4*)xb)[i] = p.v;
        if (i == 0) *maxp = -__builtin_inff();
        return;
    }
    int b2 = bid - 4096;
    const float* in     = (b2 < 1056) ? W  : cb;
    unsigned short* out = (b2 < 1056) ? WT : cosT;
    if (b2 >= 1056) b2 -= 1056;
    const int c0 = (b2 % 32) * 64;
    const int r0 = (b2 / 32) * 64;
    for (int i = tid; i < 4096; i += 256) {
        int rr = i >> 6, cc = i & 63;
        int r = r0 + rr;
        float v = (r < NFREQ) ? in[(size_t)r * LAT + c0 + cc] : 0.0f;
        t[rr][cc] = v;
    }
    __syncthreads();
    for (int i = tid; i < 4096; i += 256) {
        int cc = i >> 6, rr = i & 63;
        out[(size_t)(c0 + cc) * KPAD + (r0 + rr)] = f2bf(t[rr][cc]);
    }
}

// ---------------------------------------------------------------------------
// GEMM1: C[m][n] = sum_k A[m][k]*Bt[n][k], bf16 out.
// 128x64 block tile, 4 waves (2m x 2n of 64x32 wave tiles), BK=32, 3-stage
// circular LDS, one raw s_barrier per iter, vmcnt(3) straddle (each wave
// issues 3 DMAs/iter: 2 A-chunks + 1 B-chunk). Coalesced fetch mapping
// (round-3 scatter-mapping regression: never again). Grid 512 = 2 blocks/CU.
template <int N, int K>
__global__ __launch_bounds__(256, 2)
void gemm1_kernel(const unsigned short* __restrict__ A,
                  const unsigned short* __restrict__ Bt,
                  unsigned short* __restrict__ C) {
    __shared__ alignas(16) unsigned short As[3][128 * 32];
    __shared__ alignas(16) unsigned short Bs[3][64 * 32];

    const int tid  = threadIdx.x;
    const int wave = tid >> 6;
    const int lane = tid & 63;
    const int wm   = (wave >> 1) * 64;
    const int wn   = (wave & 1) * 32;
    const int quad = lane >> 4;
    const int l16  = lane & 15;

    const int mBase = blockIdx.y * 128;
    const int nBase = blockIdx.x * 64;

    const int srow = lane >> 2;        // coalesced: 4 lanes cover 64 contig bytes
    const int sk   = (lane & 3) * 8;

    const unsigned short* Ab1 = A  + (size_t)(mBase + (wave * 2 + 0) * 16 + srow) * K + sk;
    const unsigned short* Ab2 = A  + (size_t)(mBase + (wave * 2 + 1) * 16 + srow) * K + sk;
    const unsigned short* Bb1 = Bt + (size_t)(nBase + wave * 16 + srow) * K + sk;

    const int aoff1 = ((wave * 2 + 0) * 16) * 32;
    const int aoff2 = ((wave * 2 + 1) * 16) * 32;
    const int boff  = (wave * 16) * 32;

    constexpr int NIT = K / 32;
    // prologue: tile 0 into buffer 0
    gload_lds16(Ab1, &As[0][aoff1]);
    gload_lds16(Ab2, &As[0][aoff2]);
    gload_lds16(Bb1, &Bs[0][boff]);

    f32x4 acc[4][2] = {};
    int bc = 0;
    for (int j = 0; j < NIT; ++j) {
        const int bn = (bc == 2) ? 0 : bc + 1;
        if (j + 1 < NIT) {
            const int k0 = (j + 1) * 32;
            gload_lds16(Ab1 + k0, &As[bn][aoff1]);
            gload_lds16(Ab2 + k0, &As[bn][aoff2]);
            gload_lds16(Bb1 + k0, &Bs[bn][boff]);
            asm volatile("s_waitcnt vmcnt(3)\n\ts_barrier" ::: "memory");
        } else {
            asm volatile("s_waitcnt vmcnt(0)\n\ts_barrier" ::: "memory");
        }
        bf16x8 af[4], bfr[2];
#pragma unroll
        for (int mi = 0; mi < 4; ++mi)
            af[mi] = *(const bf16x8*)&As[bc][(wm + mi * 16 + l16) * 32 + quad * 8];
#pragma unroll
        for (int ni = 0; ni < 2; ++ni)
            bfr[ni] = *(const bf16x8*)&Bs[bc][(wn + ni * 16 + l16) * 32 + quad * 8];
#pragma unroll
        for (int mi = 0; mi < 4; ++mi)
#pragma unroll
            for (int ni = 0; ni < 2; ++ni)
                acc[mi][ni] = __builtin_amdgcn_mfma_f32_16x16x32_bf16(
                    af[mi], bfr[ni], acc[mi][ni], 0, 0, 0);
        bc = bn;
    }

    // C/D layout: col = lane&15, row = quad*4 + reg
#pragma unroll
    for (int mi = 0; mi < 4; ++mi)
#pragma unroll
        for (int ni = 0; ni < 2; ++ni) {
            int col = nBase + wn + ni * 16 + l16;
#pragma unroll
            for (int r = 0; r < 4; ++r) {
                int row = mBase + wm + mi * 16 + quad * 4 + r;
                C[(size_t)row * N + col] = f2bf(acc[mi][ni][r]);
            }
        }
}

// ---------------------------------------------------------------------------
// GEMM2: out[m][n] = sum_k A[m][k]*Bt[n][k], fp32 out + fused global max.
// 128x128 block tile, 512 threads = 8 waves (2m x 4n of 64x32 wave tiles).
// Same staging pattern/traffic as round 2 (each wave DMAs 1 A-chunk + 1
// B-chunk per iter, coalesced), but 16 waves/CU instead of 8 for latency
// hiding. 3-stage circular LDS, vmcnt(2) straddle across one raw s_barrier.
// Max: wave-reduce -> LDS -> ONE atomic per block (512 total; round 4's
// 32768 same-address atomics = 375 us -- never exceed ~1k).
template <int N, int K>
__global__ __launch_bounds__(512, 4)
void gemm2_kernel(const unsigned short* __restrict__ A,
                  const unsigned short* __restrict__ Bt,
                  float* __restrict__ C,
                  float* __restrict__ maxp) {
    __shared__ alignas(16) unsigned short As[3][128 * 32];
    __shared__ alignas(16) unsigned short Bs[3][128 * 32];
    __shared__ float redbuf[8];

    const int tid  = threadIdx.x;
    const int wave = tid >> 6;          // 0..7
    const int lane = tid & 63;
    const int wm   = (wave >> 2) * 64;  // m-half
    const int wn   = (wave & 3) * 32;   // n-quarter
    const int quad = lane >> 4;
    const int l16  = lane & 15;

    const int mBase = blockIdx.y * 128;
    const int nBase = blockIdx.x * 128;

    const int srow = lane >> 2;
    const int sk   = (lane & 3) * 8;

    const unsigned short* Ab1 = A  + (size_t)(mBase + wave * 16 + srow) * K + sk;
    const unsigned short* Bb1 = Bt + (size_t)(nBase + wave * 16 + srow) * K + sk;
    const int coff = (wave * 16) * 32;

    constexpr int NIT = K / 32;
    gload_lds16(Ab1, &As[0][coff]);
    gload_lds16(Bb1, &Bs[0][coff]);

    f32x4 acc[4][2] = {};
    int bc = 0;
    for (int j = 0; j < NIT; ++j) {
        const int bn = (bc == 2) ? 0 : bc + 1;
        if (j + 1 < NIT) {
            const int k0 = (j + 1) * 32;
            gload_lds16(Ab1 + k0, &As[bn][coff]);
            gload_lds16(Bb1 + k0, &Bs[bn][coff]);
            asm volatile("s_waitcnt vmcnt(2)\n\ts_barrier" ::: "memory");
        } else {
            asm volatile("s_waitcnt vmcnt(0)\n\ts_barrier" ::: "memory");
        }
        bf16x8 af[4], bfr[2];
#pragma unroll
        for (int mi = 0; mi < 4; ++mi)
            af[mi] = *(const bf16x8*)&As[bc][(wm + mi * 16 + l16) * 32 + quad * 8];
#pragma unroll
        for (int ni = 0; ni < 2; ++ni)
            bfr[ni] = *(const bf16x8*)&Bs[bc][(wn + ni * 16 + l16) * 32 + quad * 8];
#pragma unroll
        for (int mi = 0; mi < 4; ++mi)
#pragma unroll
            for (int ni = 0; ni < 2; ++ni)
                acc[mi][ni] = __builtin_amdgcn_mfma_f32_16x16x32_bf16(
                    af[mi], bfr[ni], acc[mi][ni], 0, 0, 0);
        bc = bn;
    }

    // epilogue: fp32 store + block max + one atomic
    float vmax = -__builtin_inff();
#pragma unroll
    for (int mi = 0; mi < 4; ++mi)
#pragma unroll
        for (int ni = 0; ni < 2; ++ni) {
            int col = nBase + wn + ni * 16 + l16;
#pragma unroll
            for (int r = 0; r < 4; ++r) {
                int row = mBase + wm + mi * 16 + quad * 4 + r;
                float v = acc[mi][ni][r];
                C[(size_t)row * N + col] = v;
                vmax = fmaxf(vmax, v);
            }
        }
#pragma unroll
    for (int off = 32; off > 0; off >>= 1)
        vmax = fmaxf(vmax, __shfl_xor(vmax, off));
    if (lane == 0) redbuf[wave] = vmax;
    __syncthreads();
    if (tid == 0) {
        float m = redbuf[0];
#pragma unroll
        for (int w = 1; w < 8; ++w) m = fmaxf(m, redbuf[w]);
        if (m >= 0.0f) atomicMax((int*)maxp, __float_as_int(m));
        else           atomicMin((unsigned int*)maxp, __float_as_uint(m));
    }
}

// ---------------------------------------------------------------------------
__global__ void scale_kernel(float* __restrict__ out, const float* __restrict__ maxp) {
    int i = blockIdx.x * blockDim.x + threadIdx.x;
    float inv = 1.0f / (*maxp);
    float4* o4 = (float4*)out;
    float4 v = o4[i];
    v.x *= inv; v.y *= inv; v.z *= inv; v.w *= inv;
    o4[i] = v;
}

// ---------------------------------------------------------------------------
extern "C" void kernel_launch(void* const* d_in, const int* in_sizes, int n_in,
                              void* d_out, int out_size, void* d_ws, size_t ws_size,
                              hipStream_t stream) {
    const float* x  = (const float*)d_in[0];  // (4096, 2048)
    const float* W  = (const float*)d_in[1];  // (2074, 2048)
    const float* cb = (const float*)d_in[2];  // (2074, 2048)

    char* ws = (char*)d_ws;
    unsigned short* xb   = (unsigned short*)ws;                                   // [4096][2048] bf16
    unsigned short* WT   = (unsigned short*)(ws + (size_t)BATCH * LAT * 2);       // [2048][2112] bf16
    unsigned short* cosT = (unsigned short*)((char*)WT + (size_t)LAT * KPAD * 2);
    unsigned short* C1   = (unsigned short*)((char*)cosT + (size_t)LAT * KPAD * 2); // [2048][2048] bf16
    float*          maxp = (float*)((char*)C1 + (size_t)LAT * LAT * 2);
    float*          out  = (float*)d_out;

    // 1. fused prep: cast x -> bf16 (+init max), transpose+cast W and cos_basis
    prep_kernel<<<4096 + 2 * 1056, 256, 0, stream>>>(x, W, cb, xb, WT, cosT, maxp);

    // 2. C1[l2][l1] = sum_f cosT[l2,f] * WT[l1,f]   (128x64 tiles, 512 blocks)
    gemm1_kernel<LAT, KPAD>
        <<<dim3(LAT / 64, LAT / 128), 256, 0, stream>>>(cosT, WT, C1);

    // 3. out[b][l2] = sum_l1 xb[b][l1] * C1[l2][l1]  (128x128, 512 thr, fused max)
    gemm2_kernel<LAT, LAT>
        <<<dim3(LAT / 128, BATCH / 128), 512, 0, stream>>>(xb, C1, out, maxp);

    // 4. out /= max
    scale_kernel<<<(out_size / 4) / 256, 256, 0, stream>>>(out, maxp);
}